// Round 2
// baseline (1146.161 us; speedup 1.0000x reference)
//
#include <hip/hip_runtime.h>
#include <cstdint>
#include <cstddef>

// ---------------------------------------------------------------------------
// MistralAttention on MI355X (gfx950), bf16 MFMA implementation.
// B=1, S=2048, H=4096, NH=32, NKV=8, HD=128, N_REP=4.
// Outputs: out (2048x4096 fp32) then attn_weights (32x2048x2048 fp32).
//
// R2 change: attn_kernel rebuilt with QBLK=128 (was 64): 4 waves x 32 q-rows.
// Per-K-tile LDS fragment reads / staging / barriers now serve 2x the q-rows
// (the kernel was ds_read_b128-issue-bound, with 4-wave broadcast waste).
// Pass 1 full-width QK (acc[2][8]); pass 2 j-halved (oac[2][8] live).
// GEMMs (R1 deep-pipelined 3-slot ring) and cvt unchanged.
// ---------------------------------------------------------------------------

#define SEQ 2048
#define HID 4096
#define NH_ 32
#define NKV_ 8
#define HD_ 128
#define KDIM_KV 1024           // NKV*HD
#define SCALING 0.08838834764831843f

typedef __bf16 bf16;
typedef __attribute__((ext_vector_type(8))) __bf16 bf16x8;
typedef __attribute__((ext_vector_type(4))) float f32x4;

__device__ __forceinline__ unsigned short f2bf(float f) {
  __bf16 h = (__bf16)f;                       // RNE
  return __builtin_bit_cast(unsigned short, h);
}
__device__ __forceinline__ float bf2f(unsigned short u) {
  unsigned int x = ((unsigned int)u) << 16;   // exact
  return __builtin_bit_cast(float, x);
}

// async global->LDS, 16B per lane. LDS dest is wave-uniform base + lane*16.
__device__ __forceinline__ void async16(const void* g, void* l) {
  __builtin_amdgcn_global_load_lds(
      (const __attribute__((address_space(1))) unsigned int*)g,
      (__attribute__((address_space(3))) unsigned int*)l, 16, 0, 0);
}

// ---------------------------------------------------------------------------
// fp32 -> bf16 conversion (vectorized float4 -> 4x bf16)
// ---------------------------------------------------------------------------
__global__ __launch_bounds__(256) void cvt_kernel(const float* __restrict__ src,
                                                  bf16* __restrict__ dst, int n4) {
  int i = blockIdx.x * 256 + threadIdx.x;
  if (i >= n4) return;
  float4 v = ((const float4*)src)[i];
  union { unsigned short u[4]; uint2 vv; } pk;
  pk.u[0] = f2bf(v.x); pk.u[1] = f2bf(v.y);
  pk.u[2] = f2bf(v.z); pk.u[3] = f2bf(v.w);
  ((uint2*)dst)[i] = pk.vv;
}

// ---------------------------------------------------------------------------
// Deep-pipelined GEMM mainloop. C tile = (AR*128) x 256, K = 4096, BK = 32.
// 512 threads = 8 waves (2M x 4N); per-wave output (AR*64) x 64.
// A is (M,K) row-major bf16, B is (N,K) row-major bf16, both k-stride 4096.
// LDS: 3-slot ring, slot = A tile (AR*128 x 32) + B tile (256 x 32), linear
// layout (row*64B + kchunk*16B) so global_load_lds dest is linear and the
// b128 frag reads are bank-uniform (16 rows x 64B contiguous per wave read).
//
// Pipeline: stages for tile t+2 are issued during tile t; before reading
// tile t we do s_waitcnt vmcnt(L) (L = loads/tile = AR+2, NEVER 0 mid-loop)
// + s_barrier. Slot (t+2)%3 == slot (t-1)%3: all waves' reads of tile t-1
// returned before they reached this barrier (compiler lgkmcnt precedes their
// MFMAs), so issuing the overwrite after the barrier is race-free. The
// sched_barrier(0) after each s_barrier pins stage-issue / ds_reads below it.
// ---------------------------------------------------------------------------
template <int AR>
__device__ __forceinline__ void gemm256_loop(const char* __restrict__ Ab,
                                             const char* __restrict__ Bb,
                                             char* smem,
                                             f32x4 (&acc)[AR * 4][4]) {
  const int NT = 128;                          // 4096 / 32
  const int tid = threadIdx.x;
  const int wid = tid >> 6, lane = tid & 63;
  const int quad = lane >> 4, l16 = lane & 15;
  const int wm = wid >> 2, wn = wid & 3;
  const int ASZ = AR * 8192;                   // A tile bytes (AR*128 rows x 64B)
  const int SLOT = ASZ + 16384;                // + B tile (256 rows x 64B)

  // per-lane global granule pointers: granule g covers (row g>>2, kchunk g&3)
  const char* gA0 = Ab + (size_t)(tid >> 2) * 8192 + (size_t)(tid & 3) * 16;
  const char* gA1 = gA0 + (size_t)128 * 8192;  // rows 128..255 (AR==2 only)
  const char* gB0 = Bb + (size_t)(tid >> 2) * 8192 + (size_t)(tid & 3) * 16;
  const char* gB1 = gB0 + (size_t)128 * 8192;  // rows 128..255
  // wave-uniform LDS round bases (offsets within slot)
  const int ldsA0 = wid * 1024;
  const int ldsB0 = ASZ + wid * 1024;

  const f32x4 fz = {0.f, 0.f, 0.f, 0.f};
#pragma unroll
  for (int m = 0; m < AR * 4; m++)
#pragma unroll
    for (int n = 0; n < 4; n++) acc[m][n] = fz;

  // prologue: stage tiles 0,1 into slots 0,1
#pragma unroll
  for (int t = 0; t < 2; t++) {
    char* sl = smem + t * SLOT;
    async16(gA0 + t * 64, sl + ldsA0);
    if (AR == 2) async16(gA1 + t * 64, sl + ldsA0 + 8192);
    async16(gB0 + t * 64, sl + ldsB0);
    async16(gB1 + t * 64, sl + ldsB0 + 8192);
  }

#pragma unroll 3
  for (int t = 0; t < NT; t++) {
    // ---------------- phase A ----------------
    if (t + 1 < NT) {
      if (AR == 2) asm volatile("s_waitcnt vmcnt(4)" ::: "memory");
      else         asm volatile("s_waitcnt vmcnt(3)" ::: "memory");
    } else {
      asm volatile("s_waitcnt vmcnt(0)" ::: "memory");
    }
    __builtin_amdgcn_s_barrier();
    __builtin_amdgcn_sched_barrier(0);
    if (t + 2 < NT) {                           // stage A of tile t+2
      char* sl = smem + ((t + 2) % 3) * SLOT;
      async16(gA0 + (size_t)(t + 2) * 64, sl + ldsA0);
      if (AR == 2) async16(gA1 + (size_t)(t + 2) * 64, sl + ldsA0 + 8192);
    }
    const bf16* sA = (const bf16*)(smem + (t % 3) * SLOT);
    const bf16* sB = (const bf16*)(smem + (t % 3) * SLOT + ASZ);
    bf16x8 a[AR * 2], b[4];
#pragma unroll
    for (int m = 0; m < AR * 2; m++)
      a[m] = *(const bf16x8*)(sA + (size_t)(wm * (AR * 64) + m * 16 + l16) * 32 + quad * 8);
#pragma unroll
    for (int n = 0; n < 4; n++)
      b[n] = *(const bf16x8*)(sB + (size_t)(wn * 64 + n * 16 + l16) * 32 + quad * 8);
    __builtin_amdgcn_s_setprio(1);
#pragma unroll
    for (int m = 0; m < AR * 2; m++)
#pragma unroll
      for (int n = 0; n < 4; n++)
        acc[m][n] = __builtin_amdgcn_mfma_f32_16x16x32_bf16(a[m], b[n], acc[m][n], 0, 0, 0);
    __builtin_amdgcn_s_setprio(0);
    // ---------------- phase B ----------------
    __builtin_amdgcn_s_barrier();
    __builtin_amdgcn_sched_barrier(0);
    if (t + 2 < NT) {                           // stage B of tile t+2
      char* sl = smem + ((t + 2) % 3) * SLOT;
      async16(gB0 + (size_t)(t + 2) * 64, sl + ldsB0);
      async16(gB1 + (size_t)(t + 2) * 64, sl + ldsB0 + 8192);
    }
#pragma unroll
    for (int m = 0; m < AR * 2; m++)
      a[m] = *(const bf16x8*)(sA + (size_t)(wm * (AR * 64) + (AR * 2 + m) * 16 + l16) * 32 + quad * 8);
    __builtin_amdgcn_s_setprio(1);
#pragma unroll
    for (int m = 0; m < AR * 2; m++)
#pragma unroll
      for (int n = 0; n < 4; n++)
        acc[AR * 2 + m][n] =
            __builtin_amdgcn_mfma_f32_16x16x32_bf16(a[m], b[n], acc[AR * 2 + m][n], 0, 0, 0);
    __builtin_amdgcn_s_setprio(0);
  }
}

// ---------------------------------------------------------------------------
// QKV projection + fused RoPE + v-transpose epilogue.
// grid (8, 24): 256x256 tiles. nt<16: Q, nt<20: K, else V.
// Epilogue: 4 chunks of 64 rows through LDS fp32 [64][265] (stride-265 pad).
// ---------------------------------------------------------------------------
__global__ __launch_bounds__(512, 2) void qkv_gemm(
    const bf16* __restrict__ A,      // hs bf16 [2048][4096]
    const bf16* __restrict__ Wq,     // [4096][4096] (n,k)
    const bf16* __restrict__ Wk,     // [1024][4096]
    const bf16* __restrict__ Wv,     // [1024][4096]
    const float* __restrict__ cosp,  // [2048][128]
    const float* __restrict__ sinp,  // [2048][128]
    bf16* __restrict__ qout,         // [2048][4096]  (post-rope)
    bf16* __restrict__ kout,         // [2048][1024]  (post-rope)
    bf16* __restrict__ vtout)        // [8][128][2048] (v transposed)
{
  extern __shared__ char smem[];     // 98304 B: 3 slots x 32768
  const int mi = blockIdx.x, nt = blockIdx.y;
  const int tid = threadIdx.x;
  const int wid = tid >> 6, lane = tid & 63;
  const int quad = lane >> 4, l16 = lane & 15;
  const int wm = wid >> 2, wn = wid & 3;

  const bf16* Bp;
  if (nt < 16)      Bp = Wq + (size_t)nt * 256 * HID;
  else if (nt < 20) Bp = Wk + (size_t)(nt - 16) * 256 * HID;
  else              Bp = Wv + (size_t)(nt - 20) * 256 * HID;

  f32x4 acc[8][4];
  gemm256_loop<2>((const char*)(A + (size_t)mi * 256 * HID), (const char*)Bp,
                  smem, acc);

  __syncthreads();                   // full drain before LDS reuse
  float* ct = (float*)smem;          // [64][265]
  for (int ch = 0; ch < 4; ch++) {
    // owning waves (wm == ch>>1) write their 64-row slab
    if (wm == (ch >> 1)) {
#pragma unroll
      for (int mm = 0; mm < 4; mm++)
#pragma unroll
        for (int n = 0; n < 4; n++)
#pragma unroll
          for (int r = 0; r < 4; r++)
            ct[(size_t)(mm * 16 + quad * 4 + r) * 265 + wn * 64 + n * 16 + l16] =
                acc[(ch & 1) * 4 + mm][n][r];
    }
    __syncthreads();
    if (nt < 20) {
      // RoPE + coalesced bf16 store. 512 thr: row r0=tid>>5 (x4 rounds), 256 cols.
      const int r0 = tid >> 5, c8 = (tid & 31) << 3;
      bf16* outp; int ldo, colbase;
      if (nt < 16) { outp = qout; ldo = HID; colbase = nt * 256; }
      else         { outp = kout; ldo = KDIM_KV; colbase = (nt - 16) * 256; }
      const int d0 = c8 & 127;
      const bool lo = d0 < 64;
#pragma unroll
      for (int p = 0; p < 4; p++) {
        int row = p * 16 + r0;
        int s = mi * 256 + ch * 64 + row;
        union { unsigned short u[8]; uint4 v; } pk;
#pragma unroll
        for (int u8 = 0; u8 < 8; u8++) {
          int c = c8 + u8;
          float x  = ct[(size_t)row * 265 + c];
          float xp = ct[(size_t)row * 265 + (c ^ 64)];
          float cv = cosp[(size_t)s * HD_ + d0 + u8];
          float sv = sinp[(size_t)s * HD_ + d0 + u8];
          pk.u[u8] = f2bf(lo ? x * cv - xp * sv : x * cv + xp * sv);
        }
        *(uint4*)(outp + (size_t)s * ldo + colbase + c8) = pk.v;
      }
    } else {
      // V transpose: thread -> (d col, 8-seq chunk), LDS-transposed read.
      const int dcol = tid & 255, sb = (tid >> 8) << 3;
      const int vh = (nt - 20) * 2 + (dcol >> 7), dd = dcol & 127;
#pragma unroll
      for (int i = 0; i < 4; i++) {
        int s8 = sb + i * 16;
        union { unsigned short u[8]; uint4 v; } pk;
#pragma unroll
        for (int u8 = 0; u8 < 8; u8++)
          pk.u[u8] = f2bf(ct[(size_t)(s8 + u8) * 265 + dcol]);
        *(uint4*)(vtout + ((size_t)vh * HD_ + dd) * SEQ + mi * 256 + ch * 64 + s8) = pk.v;
      }
    }
    __syncthreads();
  }
}

// ---------------------------------------------------------------------------
// Stage a 128x128 bf16 tile into LDS [128][136] (stride 272B -> bank-uniform
// b128 reads). Global: per round, wave reads 4 rows x 256B contiguous.
// ---------------------------------------------------------------------------
__device__ __forceinline__ void stage128(const bf16* __restrict__ base, int row_stride,
                                         unsigned short (*buf)[136], int tid) {
  const int r0 = tid >> 4;          // 0..15
  const int c = (tid & 15) * 8;     // element col, 16B chunks
#pragma unroll
  for (int g = 0; g < 8; g++) {
    int row = g * 16 + r0;
    uint4 v = *(const uint4*)(base + (size_t)row * row_stride + c);
    *(uint4*)&buf[row][c] = v;
  }
}

// ---------------------------------------------------------------------------
// Attention: one block per (head, 128-row q-tile). 512 blocks, heavy tiles
// (large qt) dispatched FIRST. 4 waves, each owns 32 q-rows (2 groups of 16).
// Two-pass exact softmax. K/V tiles staged into padded LDS; every tile's
// LDS fragment reads / staging / barriers amortize over 128 q-rows.
// ---------------------------------------------------------------------------
__global__ __launch_bounds__(256, 2) void attn_kernel(
    const bf16* __restrict__ qb,   // [2048][4096]
    const bf16* __restrict__ kb,   // [2048][1024]
    const bf16* __restrict__ vtb,  // [8][128][2048]
    float* __restrict__ wout,      // [32][2048][2048]
    bf16* __restrict__ aout)       // [2048][4096]
{
  const int bid = blockIdx.x;
  const int h = bid & 31;
  const int qt = 15 - (bid >> 5);       // descending work order
  const int kvh = h >> 2;               // N_REP = 4
  const int tid = threadIdx.x;
  const int wave = tid >> 6, lane = tid & 63;
  const int quad = lane >> 4, l16 = lane & 15;
  const int kmax = qt;                  // last 128-chunk index

  __shared__ __align__(16) unsigned short kvbuf[128][136];  // 34816 B
  __shared__ __align__(16) unsigned short wlds[128][136];   // 34816 B

  // zero-fill fully-masked columns (exp(-1e9) == 0 exactly, matches ref)
  {
    const int kc0 = (kmax + 1) * 128;
    if (kc0 < SEQ) {
      const float4 z = make_float4(0.f, 0.f, 0.f, 0.f);
      for (int row = 0; row < 128; row++) {
        float* zrow = wout + ((size_t)h * SEQ + (size_t)qt * 128 + row) * SEQ;
        for (int c = kc0 + (tid << 2); c < SEQ; c += 1024)
          *(float4*)(zrow + c) = z;
      }
    }
  }

  // q A-fragments for this wave's 32 rows (2 groups of 16), in registers
  bf16x8 aq[2][4];
#pragma unroll
  for (int g = 0; g < 2; g++) {
    const bf16* qbase = qb + ((size_t)(qt * 128) + wave * 32 + g * 16 + l16) * HID + h * HD_;
#pragma unroll
    for (int ks = 0; ks < 4; ks++)
      aq[g][ks] = *(const bf16x8*)(qbase + ks * 32 + quad * 8);
  }

  float m_[2][4], l_[2][4];
#pragma unroll
  for (int g = 0; g < 2; g++)
#pragma unroll
    for (int r = 0; r < 4; r++) { m_[g][r] = -3.0e38f; l_[g][r] = 0.f; }

  // ---- pass 1: exact row max + denom (full 8-wide QK; oac not live) ----
  for (int kt = 0; kt <= kmax; kt++) {
    __syncthreads();
    stage128(kb + (size_t)(kt * 128) * KDIM_KV + kvh * HD_, KDIM_KV, kvbuf, tid);
    __syncthreads();

    f32x4 acc[2][8];
    const f32x4 fz = {0.f, 0.f, 0.f, 0.f};
#pragma unroll
    for (int g = 0; g < 2; g++)
#pragma unroll
      for (int j = 0; j < 8; j++) acc[g][j] = fz;
#pragma unroll
    for (int ks = 0; ks < 4; ks++) {
      bf16x8 bk[8];
#pragma unroll
      for (int j = 0; j < 8; j++)
        bk[j] = *(const bf16x8*)&kvbuf[j * 16 + l16][ks * 32 + quad * 8];
#pragma unroll
      for (int g = 0; g < 2; g++)
#pragma unroll
        for (int j = 0; j < 8; j++)
          acc[g][j] = __builtin_amdgcn_mfma_f32_16x16x32_bf16(aq[g][ks], bk[j], acc[g][j], 0, 0, 0);
    }

    const bool mc = (kt == kmax);
#pragma unroll
    for (int g = 0; g < 2; g++)
#pragma unroll
      for (int r = 0; r < 4; r++) {
        int qrow = qt * 128 + wave * 32 + g * 16 + quad * 4 + r;
        float sv[8], mx = -3.0e38f;
#pragma unroll
        for (int j = 0; j < 8; j++) {
          float s = acc[g][j][r] * SCALING;
          if (mc && (kt * 128 + j * 16 + l16) > qrow) s -= 1.0e9f;
          sv[j] = s;
          mx = fmaxf(mx, s);
        }
#pragma unroll
        for (int sh = 1; sh < 16; sh <<= 1) mx = fmaxf(mx, __shfl_xor(mx, sh));
        float mn = fmaxf(m_[g][r], mx);
        float sum = 0.f;
#pragma unroll
        for (int j = 0; j < 8; j++) sum += __expf(sv[j] - mn);
#pragma unroll
        for (int sh = 1; sh < 16; sh <<= 1) sum += __shfl_xor(sum, sh);
        l_[g][r] = l_[g][r] * __expf(m_[g][r] - mn) + sum;
        m_[g][r] = mn;
      }
  }

  float linv[2][4];
#pragma unroll
  for (int g = 0; g < 2; g++)
#pragma unroll
    for (int r = 0; r < 4; r++) linv[g][r] = 1.f / l_[g][r];

  f32x4 oac[2][8];
  {
    const f32x4 fz = {0.f, 0.f, 0.f, 0.f};
#pragma unroll
    for (int g = 0; g < 2; g++)
#pragma unroll
      for (int j = 0; j < 8; j++) oac[g][j] = fz;
  }

  // ---- pass 2: recompute S (j-halved), emit weights, accumulate PV ----
  for (int kt = 0; kt <= kmax; kt++) {
    __syncthreads();   // prev chunk PV reads (kvbuf+wlds) & dump reads done
    stage128(kb + (size_t)(kt * 128) * KDIM_KV + kvh * HD_, KDIM_KV, kvbuf, tid);
    __syncthreads();   // K ready

    const bool mc = (kt == kmax);
#pragma unroll
    for (int jh = 0; jh < 2; jh++) {
      f32x4 acc[2][4];
      const f32x4 fz = {0.f, 0.f, 0.f, 0.f};
#pragma unroll
      for (int g = 0; g < 2; g++)
#pragma unroll
        for (int j = 0; j < 4; j++) acc[g][j] = fz;
#pragma unroll
      for (int ks = 0; ks < 4; ks++) {
        bf16x8 bk[4];
#pragma unroll
        for (int j = 0; j < 4; j++)
          bk[j] = *(const bf16x8*)&kvbuf[(jh * 4 + j) * 16 + l16][ks * 32 + quad * 8];
#pragma unroll
        for (int g = 0; g < 2; g++)
#pragma unroll
          for (int j = 0; j < 4; j++)
            acc[g][j] = __builtin_amdgcn_mfma_f32_16x16x32_bf16(aq[g][ks], bk[j], acc[g][j], 0, 0, 0);
      }
#pragma unroll
      for (int g = 0; g < 2; g++)
#pragma unroll
        for (int r = 0; r < 4; r++) {
          int qrow = qt * 128 + wave * 32 + g * 16 + quad * 4 + r;
#pragma unroll
          for (int j = 0; j < 4; j++) {
            float s = acc[g][j][r] * SCALING;
            if (mc && (kt * 128 + (jh * 4 + j) * 16 + l16) > qrow) s -= 1.0e9f;
            wlds[wave * 32 + g * 16 + quad * 4 + r][(jh * 4 + j) * 16 + l16] =
                f2bf(__expf(s - m_[g][r]) * linv[g][r]);
          }
        }
    }
    __syncthreads();   // kvbuf QK reads done; wlds p ready

    // stage V (overwrites kvbuf) + dump weights (reads wlds), independent
    stage128(vtb + (size_t)kvh * HD_ * SEQ + kt * 128, SEQ, kvbuf, tid);
    {
      float* wdst = wout + ((size_t)h * SEQ + (size_t)qt * 128) * SEQ + kt * 128;
      const int rr = tid >> 5, c4 = (tid & 31) << 2;
#pragma unroll
      for (int p = 0; p < 16; p++) {
        int row = p * 8 + rr;
        uint2 w = *(const uint2*)&wlds[row][c4];
        float4 v;
        v.x = bf2f((unsigned short)(w.x & 0xffff));
        v.y = bf2f((unsigned short)(w.x >> 16));
        v.z = bf2f((unsigned short)(w.y & 0xffff));
        v.w = bf2f((unsigned short)(w.y >> 16));
        *(float4*)(wdst + (size_t)row * SEQ + c4) = v;
      }
    }
    __syncthreads();   // V ready

#pragma unroll
    for (int ks = 0; ks < 4; ks++) {
      bf16x8 aw0, aw1, bv[8];
      aw0 = *(const bf16x8*)&wlds[wave * 32 + l16][ks * 32 + quad * 8];
      aw1 = *(const bf16x8*)&wlds[wave * 32 + 16 + l16][ks * 32 + quad * 8];
#pragma unroll
      for (int j = 0; j < 8; j++)
        bv[j] = *(const bf16x8*)&kvbuf[j * 16 + l16][ks * 32 + quad * 8];
#pragma unroll
      for (int j = 0; j < 8; j++)
        oac[0][j] = __builtin_amdgcn_mfma_f32_16x16x32_bf16(aw0, bv[j], oac[0][j], 0, 0, 0);
#pragma unroll
      for (int j = 0; j < 8; j++)
        oac[1][j] = __builtin_amdgcn_mfma_f32_16x16x32_bf16(aw1, bv[j], oac[1][j], 0, 0, 0);
    }
  }

  // write attn_out (bf16) via wlds for coalescing
  __syncthreads();
#pragma unroll
  for (int g = 0; g < 2; g++)
#pragma unroll
    for (int j = 0; j < 8; j++)
#pragma unroll
      for (int r = 0; r < 4; r++)
        wlds[wave * 32 + g * 16 + quad * 4 + r][j * 16 + l16] = f2bf(oac[g][j][r]);
  __syncthreads();
  {
    const int r0 = tid >> 4, c8 = (tid & 15) << 3;
    bf16* abase = aout + (size_t)(qt * 128) * HID + h * HD_;
#pragma unroll
    for (int p = 0; p < 8; p++) {
      int row = p * 16 + r0;
      union { unsigned short u[8]; uint4 v; } pk;
#pragma unroll
      for (int u8 = 0; u8 < 8; u8++) pk.u[u8] = wlds[row][c8 + u8];
      *(uint4*)(abase + (size_t)row * HID + c8) = pk.v;
    }
  }
}

// ---------------------------------------------------------------------------
// Output projection: C = attn_out(2048x4096 bf16) * wo^T, wo (4096,4096) (n,k)
// 128x256 tiles, grid (16, 16) = 256 blocks (full machine).
// ---------------------------------------------------------------------------
__global__ __launch_bounds__(512, 2) void proj_gemm(const bf16* __restrict__ A,
                                                    const bf16* __restrict__ B,
                                                    float* __restrict__ C) {
  extern __shared__ char smem[];     // 73728 B: 3 slots x 24576
  const int mi = blockIdx.x, nt = blockIdx.y;
  const int tid = threadIdx.x;
  const int lane = tid & 63;
  const int wid = tid >> 6;
  const int quad = lane >> 4, l16 = lane & 15;
  const int wm = wid >> 2, wn = wid & 3;

  f32x4 acc[4][4];
  gemm256_loop<1>((const char*)(A + (size_t)mi * 128 * HID),
                  (const char*)(B + (size_t)nt * 256 * HID), smem, acc);

#pragma unroll
  for (int m = 0; m < 4; m++)
#pragma unroll
    for (int n = 0; n < 4; n++)
#pragma unroll
      for (int r = 0; r < 4; r++) {
        int row = mi * 128 + wm * 64 + m * 16 + quad * 4 + r;
        int col = nt * 256 + wn * 64 + n * 16 + l16;
        C[(size_t)row * HID + col] = acc[m][n][r];
      }
}

// ---------------------------------------------------------------------------
// Workspace layout (bytes): total 104 MB
// ---------------------------------------------------------------------------
extern "C" void kernel_launch(void* const* d_in, const int* in_sizes, int n_in,
                              void* d_out, int out_size, void* d_ws, size_t ws_size,
                              hipStream_t stream) {
  const float* hs   = (const float*)d_in[0];
  const float* wq   = (const float*)d_in[1];
  const float* wk   = (const float*)d_in[2];
  const float* wv   = (const float*)d_in[3];
  const float* wo   = (const float*)d_in[4];
  const float* cosp = (const float*)d_in[5];
  const float* sinp = (const float*)d_in[6];

  if (ws_size < (size_t)109051904) return;  // need 104 MB scratch

  char* ws = (char*)d_ws;
  bf16* hsb = (bf16*)(ws + 0);
  bf16* wqb = (bf16*)(ws + 16777216);
  bf16* wkb = (bf16*)(ws + 50331648);
  bf16* wvb = (bf16*)(ws + 58720256);
  bf16* qb  = (bf16*)(ws + 67108864);
  bf16* kb  = (bf16*)(ws + 83886080);
  bf16* vtb = (bf16*)(ws + 88080384);
  bf16* aob = (bf16*)(ws + 92274688);

  float* outp = (float*)d_out;
  float* wout = outp + (size_t)SEQ * HID;   // attn_weights region

  // allow >64KB dynamic LDS (idempotent; not a stream op -> capture-safe)
  hipFuncSetAttribute((const void*)qkv_gemm,
                      hipFuncAttributeMaxDynamicSharedMemorySize, 98304);
  hipFuncSetAttribute((const void*)proj_gemm,
                      hipFuncAttributeMaxDynamicSharedMemorySize, 73728);

  cvt_kernel<<<2097152 / 256, 256, 0, stream>>>(hs, hsb, 2097152);
  cvt_kernel<<<4194304 / 256, 256, 0, stream>>>(wq, wqb, 4194304);
  cvt_kernel<<<1048576 / 256, 256, 0, stream>>>(wk, wkb, 1048576);
  cvt_kernel<<<1048576 / 256, 256, 0, stream>>>(wv, wvb, 1048576);

  qkv_gemm<<<dim3(8, 24), 512, 98304, stream>>>(hsb, wqb, wkb, wvb, cosp, sinp, qb, kb, vtb);

  cvt_kernel<<<4194304 / 256, 256, 0, stream>>>(wo, wqb, 4194304);  // reuse slot

  attn_kernel<<<512, 256, 0, stream>>>(qb, kb, vtb, wout, aob);

  proj_gemm<<<dim3(16, 16), 512, 73728, stream>>>(aob, wqb, outp);
}

// Round 4
// 1031.520 us; speedup vs baseline: 1.1111x; 1.1111x over previous
//
#include <hip/hip_runtime.h>
#include <cstdint>
#include <cstddef>

// ---------------------------------------------------------------------------
// MistralAttention on MI355X (gfx950), bf16 MFMA implementation.
// B=1, S=2048, H=4096, NH=32, NKV=8, HD=128, N_REP=4.
// Outputs: out (2048x4096 fp32) then attn_weights (32x2048x2048 fp32).
//
// R4 = R3 resubmitted (container-level infra failure, kernel never ran):
// attn_kernel reverted to the R1 QBLK=64 version (R2's QBLK=128 regressed:
// 2 blocks/CU occupancy + static 512-block triangular imbalance). Input-side
// cvt launches fused 4->1 (identical math). GEMMs unchanged from R1.
// ---------------------------------------------------------------------------

#define SEQ 2048
#define HID 4096
#define NH_ 32
#define NKV_ 8
#define HD_ 128
#define KDIM_KV 1024           // NKV*HD
#define SCALING 0.08838834764831843f

typedef __bf16 bf16;
typedef __attribute__((ext_vector_type(8))) __bf16 bf16x8;
typedef __attribute__((ext_vector_type(4))) float f32x4;

__device__ __forceinline__ unsigned short f2bf(float f) {
  __bf16 h = (__bf16)f;                       // RNE
  return __builtin_bit_cast(unsigned short, h);
}
__device__ __forceinline__ float bf2f(unsigned short u) {
  unsigned int x = ((unsigned int)u) << 16;   // exact
  return __builtin_bit_cast(float, x);
}

// async global->LDS, 16B per lane. LDS dest is wave-uniform base + lane*16.
__device__ __forceinline__ void async16(const void* g, void* l) {
  __builtin_amdgcn_global_load_lds(
      (const __attribute__((address_space(1))) unsigned int*)g,
      (__attribute__((address_space(3))) unsigned int*)l, 16, 0, 0);
}

// ---------------------------------------------------------------------------
// fp32 -> bf16 conversion (vectorized float4 -> 4x bf16)
// ---------------------------------------------------------------------------
__device__ __forceinline__ void cvt_one(const float* __restrict__ src,
                                        bf16* __restrict__ dst, int i) {
  float4 v = ((const float4*)src)[i];
  union { unsigned short u[4]; uint2 vv; } pk;
  pk.u[0] = f2bf(v.x); pk.u[1] = f2bf(v.y);
  pk.u[2] = f2bf(v.z); pk.u[3] = f2bf(v.w);
  ((uint2*)dst)[i] = pk.vv;
}

__global__ __launch_bounds__(256) void cvt_kernel(const float* __restrict__ src,
                                                  bf16* __restrict__ dst, int n4) {
  int i = blockIdx.x * 256 + threadIdx.x;
  if (i >= n4) return;
  cvt_one(src, dst, i);
}

// fused: hs (2097152 f4) | wq (4194304 f4) | wk (1048576 f4) | wv (1048576 f4)
// segment boundaries are multiples of 256 -> per-block uniform branch.
__global__ __launch_bounds__(256) void cvt4_kernel(
    const float* __restrict__ hs, const float* __restrict__ wq,
    const float* __restrict__ wk, const float* __restrict__ wv,
    bf16* __restrict__ hsb, bf16* __restrict__ wqb,
    bf16* __restrict__ wkb, bf16* __restrict__ wvb) {
  int i = blockIdx.x * 256 + threadIdx.x;
  if (i < 2097152) { cvt_one(hs, hsb, i); return; }
  i -= 2097152;
  if (i < 4194304) { cvt_one(wq, wqb, i); return; }
  i -= 4194304;
  if (i < 1048576) { cvt_one(wk, wkb, i); return; }
  i -= 1048576;
  cvt_one(wv, wvb, i);
}

// ---------------------------------------------------------------------------
// Deep-pipelined GEMM mainloop. C tile = (AR*128) x 256, K = 4096, BK = 32.
// 512 threads = 8 waves (2M x 4N); per-wave output (AR*64) x 64.
// A is (M,K) row-major bf16, B is (N,K) row-major bf16, both k-stride 4096.
// LDS: 3-slot ring, slot = A tile (AR*128 x 32) + B tile (256 x 32), linear
// layout (row*64B + kchunk*16B) so global_load_lds dest is linear and the
// b128 frag reads are bank-uniform (16 rows x 64B contiguous per wave read).
//
// Pipeline: stages for tile t+2 are issued during tile t; before reading
// tile t we do s_waitcnt vmcnt(L) (L = loads/tile = AR+2, NEVER 0 mid-loop)
// + s_barrier. Slot (t+2)%3 == slot (t-1)%3: all waves' reads of tile t-1
// returned before they reached this barrier (compiler lgkmcnt precedes their
// MFMAs), so issuing the overwrite after the barrier is race-free. The
// sched_barrier(0) after each s_barrier pins stage-issue / ds_reads below it.
// ---------------------------------------------------------------------------
template <int AR>
__device__ __forceinline__ void gemm256_loop(const char* __restrict__ Ab,
                                             const char* __restrict__ Bb,
                                             char* smem,
                                             f32x4 (&acc)[AR * 4][4]) {
  const int NT = 128;                          // 4096 / 32
  const int tid = threadIdx.x;
  const int wid = tid >> 6, lane = tid & 63;
  const int quad = lane >> 4, l16 = lane & 15;
  const int wm = wid >> 2, wn = wid & 3;
  const int ASZ = AR * 8192;                   // A tile bytes (AR*128 rows x 64B)
  const int SLOT = ASZ + 16384;                // + B tile (256 rows x 64B)

  // per-lane global granule pointers: granule g covers (row g>>2, kchunk g&3)
  const char* gA0 = Ab + (size_t)(tid >> 2) * 8192 + (size_t)(tid & 3) * 16;
  const char* gA1 = gA0 + (size_t)128 * 8192;  // rows 128..255 (AR==2 only)
  const char* gB0 = Bb + (size_t)(tid >> 2) * 8192 + (size_t)(tid & 3) * 16;
  const char* gB1 = gB0 + (size_t)128 * 8192;  // rows 128..255
  // wave-uniform LDS round bases (offsets within slot)
  const int ldsA0 = wid * 1024;
  const int ldsB0 = ASZ + wid * 1024;

  const f32x4 fz = {0.f, 0.f, 0.f, 0.f};
#pragma unroll
  for (int m = 0; m < AR * 4; m++)
#pragma unroll
    for (int n = 0; n < 4; n++) acc[m][n] = fz;

  // prologue: stage tiles 0,1 into slots 0,1
#pragma unroll
  for (int t = 0; t < 2; t++) {
    char* sl = smem + t * SLOT;
    async16(gA0 + t * 64, sl + ldsA0);
    if (AR == 2) async16(gA1 + t * 64, sl + ldsA0 + 8192);
    async16(gB0 + t * 64, sl + ldsB0);
    async16(gB1 + t * 64, sl + ldsB0 + 8192);
  }

#pragma unroll 3
  for (int t = 0; t < NT; t++) {
    // ---------------- phase A ----------------
    if (t + 1 < NT) {
      if (AR == 2) asm volatile("s_waitcnt vmcnt(4)" ::: "memory");
      else         asm volatile("s_waitcnt vmcnt(3)" ::: "memory");
    } else {
      asm volatile("s_waitcnt vmcnt(0)" ::: "memory");
    }
    __builtin_amdgcn_s_barrier();
    __builtin_amdgcn_sched_barrier(0);
    if (t + 2 < NT) {                           // stage A of tile t+2
      char* sl = smem + ((t + 2) % 3) * SLOT;
      async16(gA0 + (size_t)(t + 2) * 64, sl + ldsA0);
      if (AR == 2) async16(gA1 + (size_t)(t + 2) * 64, sl + ldsA0 + 8192);
    }
    const bf16* sA = (const bf16*)(smem + (t % 3) * SLOT);
    const bf16* sB = (const bf16*)(smem + (t % 3) * SLOT + ASZ);
    bf16x8 a[AR * 2], b[4];
#pragma unroll
    for (int m = 0; m < AR * 2; m++)
      a[m] = *(const bf16x8*)(sA + (size_t)(wm * (AR * 64) + m * 16 + l16) * 32 + quad * 8);
#pragma unroll
    for (int n = 0; n < 4; n++)
      b[n] = *(const bf16x8*)(sB + (size_t)(wn * 64 + n * 16 + l16) * 32 + quad * 8);
    __builtin_amdgcn_s_setprio(1);
#pragma unroll
    for (int m = 0; m < AR * 2; m++)
#pragma unroll
      for (int n = 0; n < 4; n++)
        acc[m][n] = __builtin_amdgcn_mfma_f32_16x16x32_bf16(a[m], b[n], acc[m][n], 0, 0, 0);
    __builtin_amdgcn_s_setprio(0);
    // ---------------- phase B ----------------
    __builtin_amdgcn_s_barrier();
    __builtin_amdgcn_sched_barrier(0);
    if (t + 2 < NT) {                           // stage B of tile t+2
      char* sl = smem + ((t + 2) % 3) * SLOT;
      async16(gB0 + (size_t)(t + 2) * 64, sl + ldsB0);
      async16(gB1 + (size_t)(t + 2) * 64, sl + ldsB0 + 8192);
    }
#pragma unroll
    for (int m = 0; m < AR * 2; m++)
      a[m] = *(const bf16x8*)(sA + (size_t)(wm * (AR * 64) + (AR * 2 + m) * 16 + l16) * 32 + quad * 8);
    __builtin_amdgcn_s_setprio(1);
#pragma unroll
    for (int m = 0; m < AR * 2; m++)
#pragma unroll
      for (int n = 0; n < 4; n++)
        acc[AR * 2 + m][n] =
            __builtin_amdgcn_mfma_f32_16x16x32_bf16(a[m], b[n], acc[AR * 2 + m][n], 0, 0, 0);
    __builtin_amdgcn_s_setprio(0);
  }
}

// ---------------------------------------------------------------------------
// QKV projection + fused RoPE + v-transpose epilogue.
// grid (8, 24): 256x256 tiles. nt<16: Q, nt<20: K, else V.
// Epilogue: 4 chunks of 64 rows through LDS fp32 [64][265] (stride-265 pad).
// ---------------------------------------------------------------------------
__global__ __launch_bounds__(512, 2) void qkv_gemm(
    const bf16* __restrict__ A,      // hs bf16 [2048][4096]
    const bf16* __restrict__ Wq,     // [4096][4096] (n,k)
    const bf16* __restrict__ Wk,     // [1024][4096]
    const bf16* __restrict__ Wv,     // [1024][4096]
    const float* __restrict__ cosp,  // [2048][128]
    const float* __restrict__ sinp,  // [2048][128]
    bf16* __restrict__ qout,         // [2048][4096]  (post-rope)
    bf16* __restrict__ kout,         // [2048][1024]  (post-rope)
    bf16* __restrict__ vtout)        // [8][128][2048] (v transposed)
{
  extern __shared__ char smem[];     // 98304 B: 3 slots x 32768
  const int mi = blockIdx.x, nt = blockIdx.y;
  const int tid = threadIdx.x;
  const int wid = tid >> 6, lane = tid & 63;
  const int quad = lane >> 4, l16 = lane & 15;
  const int wm = wid >> 2, wn = wid & 3;

  const bf16* Bp;
  if (nt < 16)      Bp = Wq + (size_t)nt * 256 * HID;
  else if (nt < 20) Bp = Wk + (size_t)(nt - 16) * 256 * HID;
  else              Bp = Wv + (size_t)(nt - 20) * 256 * HID;

  f32x4 acc[8][4];
  gemm256_loop<2>((const char*)(A + (size_t)mi * 256 * HID), (const char*)Bp,
                  smem, acc);

  __syncthreads();                   // full drain before LDS reuse
  float* ct = (float*)smem;          // [64][265]
  for (int ch = 0; ch < 4; ch++) {
    // owning waves (wm == ch>>1) write their 64-row slab
    if (wm == (ch >> 1)) {
#pragma unroll
      for (int mm = 0; mm < 4; mm++)
#pragma unroll
        for (int n = 0; n < 4; n++)
#pragma unroll
          for (int r = 0; r < 4; r++)
            ct[(size_t)(mm * 16 + quad * 4 + r) * 265 + wn * 64 + n * 16 + l16] =
                acc[(ch & 1) * 4 + mm][n][r];
    }
    __syncthreads();
    if (nt < 20) {
      // RoPE + coalesced bf16 store. 512 thr: row r0=tid>>5 (x4 rounds), 256 cols.
      const int r0 = tid >> 5, c8 = (tid & 31) << 3;
      bf16* outp; int ldo, colbase;
      if (nt < 16) { outp = qout; ldo = HID; colbase = nt * 256; }
      else         { outp = kout; ldo = KDIM_KV; colbase = (nt - 16) * 256; }
      const int d0 = c8 & 127;
      const bool lo = d0 < 64;
#pragma unroll
      for (int p = 0; p < 4; p++) {
        int row = p * 16 + r0;
        int s = mi * 256 + ch * 64 + row;
        union { unsigned short u[8]; uint4 v; } pk;
#pragma unroll
        for (int u8 = 0; u8 < 8; u8++) {
          int c = c8 + u8;
          float x  = ct[(size_t)row * 265 + c];
          float xp = ct[(size_t)row * 265 + (c ^ 64)];
          float cv = cosp[(size_t)s * HD_ + d0 + u8];
          float sv = sinp[(size_t)s * HD_ + d0 + u8];
          pk.u[u8] = f2bf(lo ? x * cv - xp * sv : x * cv + xp * sv);
        }
        *(uint4*)(outp + (size_t)s * ldo + colbase + c8) = pk.v;
      }
    } else {
      // V transpose: thread -> (d col, 8-seq chunk), LDS-transposed read.
      const int dcol = tid & 255, sb = (tid >> 8) << 3;
      const int vh = (nt - 20) * 2 + (dcol >> 7), dd = dcol & 127;
#pragma unroll
      for (int i = 0; i < 4; i++) {
        int s8 = sb + i * 16;
        union { unsigned short u[8]; uint4 v; } pk;
#pragma unroll
        for (int u8 = 0; u8 < 8; u8++)
          pk.u[u8] = f2bf(ct[(size_t)(s8 + u8) * 265 + dcol]);
        *(uint4*)(vtout + ((size_t)vh * HD_ + dd) * SEQ + mi * 256 + ch * 64 + s8) = pk.v;
      }
    }
    __syncthreads();
  }
}

// ---------------------------------------------------------------------------
// Stage a 128x128 bf16 tile into LDS [128][136] (stride 272B -> bank-uniform
// b128 reads). Global: per round, wave reads 4 rows x 256B contiguous.
// ---------------------------------------------------------------------------
__device__ __forceinline__ void stage128(const bf16* __restrict__ base, int row_stride,
                                         unsigned short (*buf)[136], int tid) {
  const int r0 = tid >> 4;          // 0..15
  const int c = (tid & 15) * 8;     // element col, 16B chunks
#pragma unroll
  for (int g = 0; g < 8; g++) {
    int row = g * 16 + r0;
    uint4 v = *(const uint4*)(base + (size_t)row * row_stride + c);
    *(uint4*)&buf[row][c] = v;
  }
}

// ---------------------------------------------------------------------------
// Attention: one block per (head, 64-row q-tile). 1024 blocks, heavy tiles
// (large qt) dispatched FIRST. 4 waves, each owns 16 q-rows. Two-pass exact
// softmax. K/V tiles staged once per block into padded LDS.
// (R1 version, verbatim: 3 blocks/CU, dynamic refill balances the triangle.)
// ---------------------------------------------------------------------------
__global__ __launch_bounds__(256, 3) void attn_kernel(
    const bf16* __restrict__ qb,   // [2048][4096]
    const bf16* __restrict__ kb,   // [2048][1024]
    const bf16* __restrict__ vtb,  // [8][128][2048]
    float* __restrict__ wout,      // [32][2048][2048]
    bf16* __restrict__ aout)       // [2048][4096]
{
  const int bid = blockIdx.x;
  const int h = bid & 31;
  const int qt = 31 - (bid >> 5);       // descending work order
  const int kvh = h >> 2;               // N_REP = 4
  const int tid = threadIdx.x;
  const int wave = tid >> 6, lane = tid & 63;
  const int quad = lane >> 4, l16 = lane & 15;
  const int kmax = qt >> 1;             // last 128-chunk index

  __shared__ __align__(16) unsigned short kvbuf[128][136];  // 34816 B
  __shared__ __align__(16) unsigned short wlds[64][136];    // 17408 B

  // zero-fill fully-masked columns (exp(-1e9) == 0 exactly, matches ref)
  {
    const int kc0 = (kmax + 1) * 128;
    if (kc0 < SEQ) {
      const float4 z = make_float4(0.f, 0.f, 0.f, 0.f);
      for (int row = 0; row < 64; row++) {
        float* zrow = wout + ((size_t)h * SEQ + (size_t)qt * 64 + row) * SEQ;
        for (int c = kc0 + (tid << 2); c < SEQ; c += 1024)
          *(float4*)(zrow + c) = z;
      }
    }
  }

  // q A-fragments for this wave's 16 rows, cached in registers
  bf16x8 aq[4];
  {
    const bf16* qbase = qb + ((size_t)(qt * 64) + wave * 16 + l16) * HID + h * HD_;
#pragma unroll
    for (int ks = 0; ks < 4; ks++)
      aq[ks] = *(const bf16x8*)(qbase + ks * 32 + quad * 8);
  }

  float m_[4], l_[4];
#pragma unroll
  for (int r = 0; r < 4; r++) { m_[r] = -3.0e38f; l_[r] = 0.f; }

  // ---- pass 1: exact row max + denom ----
  for (int kt = 0; kt <= kmax; kt++) {
    __syncthreads();
    stage128(kb + (size_t)(kt * 128) * KDIM_KV + kvh * HD_, KDIM_KV, kvbuf, tid);
    __syncthreads();

    f32x4 acc[8];
    const f32x4 fz = {0.f, 0.f, 0.f, 0.f};
#pragma unroll
    for (int j = 0; j < 8; j++) acc[j] = fz;
#pragma unroll
    for (int ks = 0; ks < 4; ks++) {
      bf16x8 bk[8];
#pragma unroll
      for (int j = 0; j < 8; j++)
        bk[j] = *(const bf16x8*)&kvbuf[j * 16 + l16][ks * 32 + quad * 8];
#pragma unroll
      for (int j = 0; j < 8; j++)
        acc[j] = __builtin_amdgcn_mfma_f32_16x16x32_bf16(aq[ks], bk[j], acc[j], 0, 0, 0);
    }

    const bool mc = (kt == kmax);
#pragma unroll
    for (int r = 0; r < 4; r++) {
      int qrow = qt * 64 + wave * 16 + quad * 4 + r;
      float sv[8], mx = -3.0e38f;
#pragma unroll
      for (int j = 0; j < 8; j++) {
        float s = acc[j][r] * SCALING;
        if (mc && (kt * 128 + j * 16 + l16) > qrow) s -= 1.0e9f;
        sv[j] = s;
        mx = fmaxf(mx, s);
      }
#pragma unroll
      for (int sh = 1; sh < 16; sh <<= 1) mx = fmaxf(mx, __shfl_xor(mx, sh));
      float mn = fmaxf(m_[r], mx);
      float sum = 0.f;
#pragma unroll
      for (int j = 0; j < 8; j++) sum += __expf(sv[j] - mn);
#pragma unroll
      for (int sh = 1; sh < 16; sh <<= 1) sum += __shfl_xor(sum, sh);
      l_[r] = l_[r] * __expf(m_[r] - mn) + sum;
      m_[r] = mn;
    }
  }

  float linv[4];
#pragma unroll
  for (int r = 0; r < 4; r++) linv[r] = 1.f / l_[r];

  f32x4 oac[8];
  {
    const f32x4 fz = {0.f, 0.f, 0.f, 0.f};
#pragma unroll
    for (int j = 0; j < 8; j++) oac[j] = fz;
  }

  // ---- pass 2: recompute S, emit weights, accumulate PV ----
  for (int kt = 0; kt <= kmax; kt++) {
    __syncthreads();   // prev chunk PV reads (kvbuf+wlds) & dump reads done
    stage128(kb + (size_t)(kt * 128) * KDIM_KV + kvh * HD_, KDIM_KV, kvbuf, tid);
    __syncthreads();   // K ready

    f32x4 acc[8];
    const f32x4 fz = {0.f, 0.f, 0.f, 0.f};
#pragma unroll
    for (int j = 0; j < 8; j++) acc[j] = fz;
#pragma unroll
    for (int ks = 0; ks < 4; ks++) {
      bf16x8 bk[8];
#pragma unroll
      for (int j = 0; j < 8; j++)
        bk[j] = *(const bf16x8*)&kvbuf[j * 16 + l16][ks * 32 + quad * 8];
#pragma unroll
      for (int j = 0; j < 8; j++)
        acc[j] = __builtin_amdgcn_mfma_f32_16x16x32_bf16(aq[ks], bk[j], acc[j], 0, 0, 0);
    }

    const bool mc = (kt == kmax);
#pragma unroll
    for (int r = 0; r < 4; r++) {
      int qrow = qt * 64 + wave * 16 + quad * 4 + r;
#pragma unroll
      for (int j = 0; j < 8; j++) {
        float s = acc[j][r] * SCALING;
        if (mc && (kt * 128 + j * 16 + l16) > qrow) s -= 1.0e9f;
        wlds[wave * 16 + quad * 4 + r][j * 16 + l16] = f2bf(__expf(s - m_[r]) * linv[r]);
      }
    }
    __syncthreads();   // kvbuf QK reads done; wlds p ready

    // stage V (overwrites kvbuf) + dump weights (reads wlds), independent
    stage128(vtb + (size_t)kvh * HD_ * SEQ + kt * 128, SEQ, kvbuf, tid);
    {
      float* wdst = wout + ((size_t)h * SEQ + (size_t)qt * 64) * SEQ + kt * 128;
      const int rr = tid >> 5, c4 = (tid & 31) << 2;
#pragma unroll
      for (int p = 0; p < 8; p++) {
        int row = p * 8 + rr;
        uint2 w = *(const uint2*)&wlds[row][c4];
        float4 v;
        v.x = bf2f((unsigned short)(w.x & 0xffff));
        v.y = bf2f((unsigned short)(w.x >> 16));
        v.z = bf2f((unsigned short)(w.y & 0xffff));
        v.w = bf2f((unsigned short)(w.y >> 16));
        *(float4*)(wdst + (size_t)row * SEQ + c4) = v;
      }
    }
    __syncthreads();   // V ready

#pragma unroll
    for (int ks = 0; ks < 4; ks++) {
      bf16x8 aw, bv[8];
      aw = *(const bf16x8*)&wlds[wave * 16 + l16][ks * 32 + quad * 8];
#pragma unroll
      for (int j = 0; j < 8; j++)
        bv[j] = *(const bf16x8*)&kvbuf[j * 16 + l16][ks * 32 + quad * 8];
#pragma unroll
      for (int j = 0; j < 8; j++)
        oac[j] = __builtin_amdgcn_mfma_f32_16x16x32_bf16(aw, bv[j], oac[j], 0, 0, 0);
    }
  }

  // write attn_out (bf16) via wlds for coalescing
  __syncthreads();
#pragma unroll
  for (int j = 0; j < 8; j++)
#pragma unroll
    for (int r = 0; r < 4; r++)
      wlds[wave * 16 + quad * 4 + r][j * 16 + l16] = f2bf(oac[j][r]);
  __syncthreads();
  {
    const int r0 = tid >> 4, c8 = (tid & 15) << 3;
    bf16* abase = aout + (size_t)(qt * 64) * HID + h * HD_;
#pragma unroll
    for (int p = 0; p < 4; p++) {
      int row = p * 16 + r0;
      union { unsigned short u[8]; uint4 v; } pk;
#pragma unroll
      for (int u8 = 0; u8 < 8; u8++) pk.u[u8] = wlds[row][c8 + u8];
      *(uint4*)(abase + (size_t)row * HID + c8) = pk.v;
    }
  }
}

// ---------------------------------------------------------------------------
// Output projection: C = attn_out(2048x4096 bf16) * wo^T, wo (4096,4096) (n,k)
// 128x256 tiles, grid (16, 16) = 256 blocks (full machine).
// ---------------------------------------------------------------------------
__global__ __launch_bounds__(512, 2) void proj_gemm(const bf16* __restrict__ A,
                                                    const bf16* __restrict__ B,
                                                    float* __restrict__ C) {
  extern __shared__ char smem[];     // 73728 B: 3 slots x 24576
  const int mi = blockIdx.x, nt = blockIdx.y;
  const int tid = threadIdx.x;
  const int lane = tid & 63;
  const int wid = tid >> 6;
  const int quad = lane >> 4, l16 = lane & 15;
  const int wm = wid >> 2, wn = wid & 3;

  f32x4 acc[4][4];
  gemm256_loop<1>((const char*)(A + (size_t)mi * 128 * HID),
                  (const char*)(B + (size_t)nt * 256 * HID), smem, acc);

#pragma unroll
  for (int m = 0; m < 4; m++)
#pragma unroll
    for (int n = 0; n < 4; n++)
#pragma unroll
      for (int r = 0; r < 4; r++) {
        int row = mi * 128 + wm * 64 + m * 16 + quad * 4 + r;
        int col = nt * 256 + wn * 64 + n * 16 + l16;
        C[(size_t)row * HID + col] = acc[m][n][r];
      }
}

// ---------------------------------------------------------------------------
// Workspace layout (bytes): total 104 MB
// ---------------------------------------------------------------------------
extern "C" void kernel_launch(void* const* d_in, const int* in_sizes, int n_in,
                              void* d_out, int out_size, void* d_ws, size_t ws_size,
                              hipStream_t stream) {
  const float* hs   = (const float*)d_in[0];
  const float* wq   = (const float*)d_in[1];
  const float* wk   = (const float*)d_in[2];
  const float* wv   = (const float*)d_in[3];
  const float* wo   = (const float*)d_in[4];
  const float* cosp = (const float*)d_in[5];
  const float* sinp = (const float*)d_in[6];

  if (ws_size < (size_t)109051904) return;  // need 104 MB scratch

  char* ws = (char*)d_ws;
  bf16* hsb = (bf16*)(ws + 0);
  bf16* wqb = (bf16*)(ws + 16777216);
  bf16* wkb = (bf16*)(ws + 50331648);
  bf16* wvb = (bf16*)(ws + 58720256);
  bf16* qb  = (bf16*)(ws + 67108864);
  bf16* kb  = (bf16*)(ws + 83886080);
  bf16* vtb = (bf16*)(ws + 88080384);
  bf16* aob = (bf16*)(ws + 92274688);

  float* outp = (float*)d_out;
  float* wout = outp + (size_t)SEQ * HID;   // attn_weights region

  // allow >64KB dynamic LDS (idempotent; not a stream op -> capture-safe)
  hipFuncSetAttribute((const void*)qkv_gemm,
                      hipFuncAttributeMaxDynamicSharedMemorySize, 98304);
  hipFuncSetAttribute((const void*)proj_gemm,
                      hipFuncAttributeMaxDynamicSharedMemorySize, 73728);

  // fused input-side conversions: hs | wq | wk | wv  (8388608 float4 total)
  cvt4_kernel<<<8388608 / 256, 256, 0, stream>>>(hs, wq, wk, wv, hsb, wqb, wkb, wvb);

  qkv_gemm<<<dim3(8, 24), 512, 98304, stream>>>(hsb, wqb, wkb, wvb, cosp, sinp, qb, kb, vtb);

  cvt_kernel<<<4194304 / 256, 256, 0, stream>>>(wo, wqb, 4194304);  // reuse slot

  attn_kernel<<<1024, 256, 0, stream>>>(qb, kb, vtb, wout, aob);

  proj_gemm<<<dim3(16, 16), 512, 73728, stream>>>(aob, wqb, outp);
}